// Round 1
// 1301.254 us; speedup vs baseline: 1.2096x; 1.2096x over previous
//
#include <hip/hip_runtime.h>

typedef __bf16 bf16x8 __attribute__((ext_vector_type(8)));
typedef float  f32x4  __attribute__((ext_vector_type(4)));
typedef unsigned long long u64;

#define AGENT __HIP_MEMORY_SCOPE_AGENT

__device__ __forceinline__ float fast_tanh(float x) {
    float e = __expf(2.0f * x);
    return 1.0f - 2.0f * __builtin_amdgcn_rcpf(e + 1.0f);
}

// Raw barrier: drain ONLY LDS ops (cross-wave hread/hist visibility), let
// global loads/stores stay in flight. __syncthreads() would emit
// s_waitcnt vmcnt(0) before s_barrier, serializing the xp prefetch and the
// states/mailbox store-acks into every step (the ~2000cy/step mystery).
__device__ __forceinline__ void lds_barrier() {
    asm volatile("s_waitcnt lgkmcnt(0)" ::: "memory");
    __builtin_amdgcn_s_barrier();
}

// ---------------------------------------------------------------------------
// Kernel 1: xproj = x @ Wih^T + bih -> fp32 into d_out's states region.
// ---------------------------------------------------------------------------
__global__ __launch_bounds__(256) void xproj_gemm_kernel(
    const float* __restrict__ x, const float* __restrict__ Wih,
    const float* __restrict__ bih, float* __restrict__ out)
{
    __shared__ __bf16 Ash[64][72];
    __shared__ __bf16 Bsh[64][72];

    const int tid  = threadIdx.x;
    const int wave = tid >> 6, lane = tid & 63;
    const int col  = lane & 15, kq = lane >> 4;
    const int bt0  = blockIdx.x * 64;
    const int h0   = blockIdx.y * 64;

    f32x4 acc[4];
#pragma unroll
    for (int nt = 0; nt < 4; ++nt) acc[nt] = (f32x4){0.f, 0.f, 0.f, 0.f};

    const int r  = tid >> 2;
    const int cb = (tid & 3) * 16;

    for (int k0 = 0; k0 < 512; k0 += 64) {
        const float* ax = x   + (size_t)(bt0 + r) * 512 + k0 + cb;
        const float* bx = Wih + (size_t)(h0  + r) * 512 + k0 + cb;
#pragma unroll
        for (int j = 0; j < 4; ++j) {
            const float4 av = ((const float4*)ax)[j];
            const float4 bv = ((const float4*)bx)[j];
            const int c = cb + 4 * j;
            Ash[r][c+0]=(__bf16)av.x; Ash[r][c+1]=(__bf16)av.y;
            Ash[r][c+2]=(__bf16)av.z; Ash[r][c+3]=(__bf16)av.w;
            Bsh[r][c+0]=(__bf16)bv.x; Bsh[r][c+1]=(__bf16)bv.y;
            Bsh[r][c+2]=(__bf16)bv.z; Bsh[r][c+3]=(__bf16)bv.w;
        }
        __syncthreads();
#pragma unroll
        for (int kt = 0; kt < 2; ++kt) {
            bf16x8 a = *(const bf16x8*)&Ash[wave * 16 + col][kt * 32 + kq * 8];
#pragma unroll
            for (int nt = 0; nt < 4; ++nt) {
                bf16x8 bb = *(const bf16x8*)&Bsh[nt * 16 + col][kt * 32 + kq * 8];
                acc[nt] = __builtin_amdgcn_mfma_f32_16x16x32_bf16(a, bb, acc[nt], 0, 0, 0);
            }
        }
        __syncthreads();
    }
#pragma unroll
    for (int nt = 0; nt < 4; ++nt) {
        const float bv = bih[h0 + nt * 16 + col];
#pragma unroll
        for (int reg = 0; reg < 4; ++reg) {
            const int m = bt0 + wave * 16 + kq * 4 + reg;
            out[(size_t)m * 512 + h0 + nt * 16 + col] = acc[nt][reg] + bv;
        }
    }
}

// ---------------------------------------------------------------------------
// Kernel 2: recurrence. 128 blocks = 32 batches x 4 weight-stationary slices.
// Two-phase K-ordered step; raw lgkm-only barriers keep global ops in flight.
// ---------------------------------------------------------------------------
__global__ __launch_bounds__(256) void lagrange_rnn_kernel(
    const float* __restrict__ Whh, const float* __restrict__ bhh,
    const float* __restrict__ kern, float* __restrict__ out,
    u64* __restrict__ mbox)
{
    const int id   = blockIdx.x;                 // 0..127
    const int b    = (id & 7) + ((id >> 5) << 3);// batch 0..31 (group on one XCD)
    const int p    = (id >> 3) & 3;              // slice member 0..3
    const int tid  = threadIdx.x;
    const int wave = tid >> 6, lane = tid & 63;
    const int col  = lane & 15, kq = lane >> 4;

    __shared__ float  hist[4][512];    // circular h history, fp32
    __shared__ __bf16 hread[2][512];   // parity double-buffered MFMA A operand

    for (int i = tid; i < 2048; i += 256) ((float*)hist)[i] = 0.f;
    for (int i = tid; i < 512;  i += 256) { hread[0][i] = (__bf16)0.f; hread[1][i] = (__bf16)0.f; }

    // --- weight fragments, K-reordered: wf[j] <-> global K-tile (4p+j)&15
    const int hA = p * 128 + wave * 32 + col;
    const int hB = hA + 16;
    bf16x8 wf0[16], wf1[16];
#pragma unroll
    for (int j = 0; j < 16; ++j) {
        const int ktg = ((j + 4 * p) & 15) * 32 + kq * 8;
        const float* s0 = Whh + (size_t)hA * 512 + ktg;
        const float* s1 = Whh + (size_t)hB * 512 + ktg;
        const float4 a0 = *(const float4*)s0, a1 = *(const float4*)(s0 + 4);
        const float4 b0 = *(const float4*)s1, b1 = *(const float4*)(s1 + 4);
        bf16x8 w;
        w[0]=(__bf16)a0.x; w[1]=(__bf16)a0.y; w[2]=(__bf16)a0.z; w[3]=(__bf16)a0.w;
        w[4]=(__bf16)a1.x; w[5]=(__bf16)a1.y; w[6]=(__bf16)a1.z; w[7]=(__bf16)a1.w;
        wf0[j] = w;
        w[0]=(__bf16)b0.x; w[1]=(__bf16)b0.y; w[2]=(__bf16)b0.z; w[3]=(__bf16)b0.w;
        w[4]=(__bf16)b1.x; w[5]=(__bf16)b1.y; w[6]=(__bf16)b1.z; w[7]=(__bf16)b1.w;
        wf1[j] = w;
    }
    const float k0 = kern[0], k1 = kern[1], k2 = kern[2], k3 = kern[3];
    const float bA = bhh[hA], bB = bhh[hB];
    float* stA = out + (size_t)b * 1024 * 512 + hA;
    const int peer = (p + wave) & 3;              // waves 1..3 poll this peer
    const int j0 = peer * 128 + lane * 2;
    const bool comp = (lane < 16);
    // hread element index base for A operand of wf[j]: ((4p+j)&15)*32 + kq*8
    const int abase = p * 128 + kq * 8;           // j-th A addr = (abase + 32j) & 511

    float xA = 0.f, xB = 0.f;
    __syncthreads();
    if (comp) { xA = stA[0]; xB = stA[16]; }      // xp(0)

    for (int t = 0; t < 1024; ++t) {
        const int rb = t & 1, wb = rb ^ 1;
        const int rt = t & 3;
        const int rm1 = (t + 3) & 3, rm2 = (t + 2) & 3, rm3 = (t + 1) & 3;
        const u64* mb_peer = mbox + (size_t)(((b << 1) | rb) * 4 + peer) * 128;
        const bool polling = (t != 0) && (wave != 0);
        const unsigned want = (unsigned)t;

        // --- xp(t+1) prefetch issued EARLIEST (max slack; barriers won't drain it)
        float nxA = 0.f, nxB = 0.f;
        if (comp) {
            nxA = stA[(size_t)(t + 1) * 512];
            nxB = stA[(size_t)(t + 1) * 512 + 16];
        }
        // --- first poll iteration issued before barA (in flight across barrier)
        u64 v0 = 0, v1 = 0;
        if (polling) {
            v0 = __hip_atomic_load(&mb_peer[lane * 2],     __ATOMIC_RELAXED, AGENT);
            v1 = __hip_atomic_load(&mb_peer[lane * 2 + 1], __ATOMIC_RELAXED, AGENT);
        }

        lds_barrier();   // barA: prev-step LDS deposits visible (lgkm only)

        // --- phase 1: own-K MFMAs (j=0..3) — operands produced locally last step
        f32x4 acc0 = (f32x4){0,0,0,0}, acc1 = (f32x4){0,0,0,0};
#pragma unroll
        for (int j = 0; j < 4; ++j) {
            bf16x8 a = *(const bf16x8*)&hread[rb][(abase + 32 * j) & 511];
            acc0 = __builtin_amdgcn_mfma_f32_16x16x32_bf16(a, wf0[j], acc0, 0, 0, 0);
            acc1 = __builtin_amdgcn_mfma_f32_16x16x32_bf16(a, wf1[j], acc1, 0, 0, 0);
        }

        // --- complete poll for h(t-1) (tag t), deposit hread(t)[peer] + hist
        if (polling) {
            while ((unsigned)(v0 >> 32) != want || (unsigned)(v1 >> 32) != want) {
                v0 = __hip_atomic_load(&mb_peer[lane * 2],     __ATOMIC_RELAXED, AGENT);
                v1 = __hip_atomic_load(&mb_peer[lane * 2 + 1], __ATOMIC_RELAXED, AGENT);
            }
            union { unsigned u; float f; } d0, d1;
            d0.u = (unsigned)v0; d1.u = (unsigned)v1;
            // hread(t)[peer] = k0*h(t-1) + k1*h(t-2) + k2*h(t-3) + k3*h(t-4)
            const float q0 = k1 * hist[rm2][j0]     + k2 * hist[rm3][j0]     + k3 * hist[rt][j0];
            const float q1 = k1 * hist[rm2][j0 + 1] + k2 * hist[rm3][j0 + 1] + k3 * hist[rt][j0 + 1];
            hread[rb][j0]     = (__bf16)(q0 + k0 * d0.f);
            hread[rb][j0 + 1] = (__bf16)(q1 + k0 * d1.f);
            hist[rm1][j0]     = d0.f;
            hist[rm1][j0 + 1] = d1.f;
        }

        lds_barrier();   // barB: poll deposits visible (lgkm only)

        // --- Lagrange partial for own hread(t+1): k1 h(t-1)+k2 h(t-2)+k3 h(t-3)
        float ppA = 0.f, ppB = 0.f;
        if (comp) {
            ppA = k1 * hist[rm1][hA] + k2 * hist[rm2][hA] + k3 * hist[rm3][hA];
            ppB = k1 * hist[rm1][hB] + k2 * hist[rm2][hB] + k3 * hist[rm3][hB];
        }

        // --- phase 2: peer-K MFMAs (j=4..15), 6 fresh chains (4-deep) for ILP
        f32x4 c0a = (f32x4){0,0,0,0}, c0b = (f32x4){0,0,0,0}, c0c = (f32x4){0,0,0,0};
        f32x4 c1a = (f32x4){0,0,0,0}, c1b = (f32x4){0,0,0,0}, c1c = (f32x4){0,0,0,0};
#pragma unroll
        for (int j = 4; j < 8; ++j) {
            bf16x8 a = *(const bf16x8*)&hread[rb][(abase + 32 * j) & 511];
            c0a = __builtin_amdgcn_mfma_f32_16x16x32_bf16(a, wf0[j], c0a, 0, 0, 0);
            c1a = __builtin_amdgcn_mfma_f32_16x16x32_bf16(a, wf1[j], c1a, 0, 0, 0);
        }
#pragma unroll
        for (int j = 8; j < 12; ++j) {
            bf16x8 a = *(const bf16x8*)&hread[rb][(abase + 32 * j) & 511];
            c0b = __builtin_amdgcn_mfma_f32_16x16x32_bf16(a, wf0[j], c0b, 0, 0, 0);
            c1b = __builtin_amdgcn_mfma_f32_16x16x32_bf16(a, wf1[j], c1b, 0, 0, 0);
        }
#pragma unroll
        for (int j = 12; j < 16; ++j) {
            bf16x8 a = *(const bf16x8*)&hread[rb][(abase + 32 * j) & 511];
            c0c = __builtin_amdgcn_mfma_f32_16x16x32_bf16(a, wf0[j], c0c, 0, 0, 0);
            c1c = __builtin_amdgcn_mfma_f32_16x16x32_bf16(a, wf1[j], c1c, 0, 0, 0);
        }

        // --- tanh -> ship h(t) (tag t+1, parity wb) -> states -> own deposits
        if (comp) {
            const float hAv = fast_tanh(xA + acc0[0] + c0a[0] + c0b[0] + c0c[0] + bA);
            const float hBv = fast_tanh(xB + acc1[0] + c1a[0] + c1b[0] + c1c[0] + bB);
            u64* mb_self = mbox + (size_t)(((b << 1) | wb) * 4 + p) * 128;
            const u64 tag = (u64)(unsigned)(t + 1) << 32;
            union { float f; unsigned u; } cA, cB;
            cA.f = hAv; cB.f = hBv;
            __hip_atomic_store(&mb_self[wave * 32 + col],      tag | cA.u, __ATOMIC_RELAXED, AGENT);
            __hip_atomic_store(&mb_self[wave * 32 + col + 16], tag | cB.u, __ATOMIC_RELAXED, AGENT);
            stA[(size_t)t * 512]      = hAv;
            stA[(size_t)t * 512 + 16] = hBv;
            hist[rt][hA] = hAv;  hread[wb][hA] = (__bf16)(ppA + k0 * hAv);
            hist[rt][hB] = hBv;  hread[wb][hB] = (__bf16)(ppB + k0 * hBv);
        }
        xA = nxA; xB = nxB;
    }

    // final state output: each block writes its OWN slice of h(1023) (row 3)
    float* out2 = out + (size_t)32 * 1024 * 512 + (size_t)b * 512;
    if (comp) {
        out2[hA] = hist[3][hA];
        out2[hB] = hist[3][hB];
    }
}

// ---------------------------------------------------------------------------
extern "C" void kernel_launch(void* const* d_in, const int* in_sizes, int n_in,
                              void* d_out, int out_size, void* d_ws, size_t ws_size,
                              hipStream_t stream) {
    const float* x    = (const float*)d_in[0];   // [32,1024,512]
    const float* Wih  = (const float*)d_in[1];   // [512,512]
    const float* Whh  = (const float*)d_in[2];   // [512,512]
    const float* bih  = (const float*)d_in[3];   // [512]
    const float* bhh  = (const float*)d_in[4];   // [512]
    const float* kern = (const float*)d_in[5];   // [4]
    float* out = (float*)d_out;

    // mailboxes: 32 batches x 2 parity x 4 slices x 128 tagged u64 = 256 KB.
    // No init needed: exact tag match; 0xAAAAAAAA poison can't match.
    u64* mbox = (u64*)d_ws;

    dim3 g1(512, 8, 1);
    xproj_gemm_kernel<<<g1, 256, 0, stream>>>(x, Wih, bih, out);
    lagrange_rnn_kernel<<<128, 256, 0, stream>>>(Whh, bhh, kern, out, mbox);
}